// Round 1
// baseline (918.191 us; speedup 1.0000x reference)
//
#include <hip/hip_runtime.h>

#define DHID 10

__global__ __launch_bounds__(64) void ode_rows_kernel(
    const float* __restrict__ thr,   // B x (N+1)
    const float* __restrict__ DOD,   // B
    const float* __restrict__ Vav,   // B
    const float* __restrict__ C0,    // B
    const float* __restrict__ R0,    // B
    const float* __restrict__ W1,    // 10 x 5
    const float* __restrict__ b1,    // 10
    const float* __restrict__ W2,    // 5 x 10
    const float* __restrict__ b2,    // 5
    float* __restrict__ out,         // B x (N+1) x 2
    int B, int N)
{
    int row = blockIdx.x * blockDim.x + threadIdx.x;
    if (row >= B) return;

    const float dod = DOD[row], vav = Vav[row];
    float y3 = C0[row], y4 = R0[row];

    // tanh(x) = 1 - 2/(1 + e^{2x}).  Pre-fold 2*log2(e) into layer-1 weights
    // so x is already the exp2 argument.  Fold "+1" terms into c3/c4 and the
    // "-2" into the layer-2 weights.
    const float k2 = 2.0f * 1.4426950408889634f; // 2*log2(e)
    float bw[DHID], w0k[DHID], w3k[DHID], w4k[DHID], w2a[DHID], w2b[DHID];
    float c3 = b2[3], c4 = b2[4];
#pragma unroll
    for (int h = 0; h < DHID; ++h) {
        float w1h0 = W1[h * 5 + 0];
        float w1h1 = W1[h * 5 + 1];
        float w1h2 = W1[h * 5 + 2];
        float w1h3 = W1[h * 5 + 3];
        float w1h4 = W1[h * 5 + 4];
        // per-row constant part of the hidden pre-activation (cols 1,2 of the
        // state never change: DOD, V_av)
        bw[h]  = k2 * (b1[h] + w1h1 * dod + w1h2 * vav);
        w0k[h] = k2 * w1h0;
        w3k[h] = k2 * w1h3;
        w4k[h] = k2 * w1h4;
        float v3 = W2[3 * 10 + h];
        float v4 = W2[4 * 10 + h];
        c3 += v3;
        c4 += v4;
        w2a[h] = -2.0f * v3;
        w2b[h] = -2.0f * v4;
    }

    const float* trp = thr + (size_t)row * (size_t)(N + 1);
    float2* orow = (float2*)(out + (size_t)row * (size_t)(N + 1) * 2);
    orow[0] = make_float2(y3, y4);

    float t_cur = trp[0];
    float t_nxt = trp[1];
    for (int i = 0; i < N; ++i) {
        // prefetch 2 ahead (used as t_nxt in the next iteration)
        float t_fut = (i + 2 <= N) ? trp[i + 2] : 0.0f;
        float hstep = t_nxt - t_cur;

        float a3 = c3, a4 = c4;
#pragma unroll
        for (int h = 0; h < DHID; ++h) {
            float x = bw[h];
            x = fmaf(w0k[h], t_cur, x);
            x = fmaf(w3k[h], y3, x);
            x = fmaf(w4k[h], y4, x);
            float e = __builtin_amdgcn_exp2f(x);      // e^{2*pre}
            float s = __builtin_amdgcn_rcpf(1.0f + e); // 1/(1+e^{2x})
            a3 = fmaf(w2a[h], s, a3);
            a4 = fmaf(w2b[h], s, a4);
        }
        y3 = fmaf(hstep, a3, y3);
        y4 = fmaf(hstep, a4, y4);
        orow[i + 1] = make_float2(y3, y4);

        t_cur = t_nxt;
        t_nxt = t_fut;
    }
}

extern "C" void kernel_launch(void* const* d_in, const int* in_sizes, int n_in,
                              void* d_out, int out_size, void* d_ws, size_t ws_size,
                              hipStream_t stream) {
    const float* thr = (const float*)d_in[0];
    const float* DOD = (const float*)d_in[1];
    const float* Vav = (const float*)d_in[2];
    const float* C0  = (const float*)d_in[3];
    const float* R0  = (const float*)d_in[4];
    const float* W1  = (const float*)d_in[5];
    const float* b1  = (const float*)d_in[6];
    const float* W2  = (const float*)d_in[7];
    const float* b2  = (const float*)d_in[8];
    float* out = (float*)d_out;

    int B = in_sizes[1];                 // DOD is (1,B)
    int N = in_sizes[0] / B - 1;         // throughput is (B, N+1)

    dim3 block(64);
    dim3 grid((B + 63) / 64);
    ode_rows_kernel<<<grid, block, 0, stream>>>(thr, DOD, Vav, C0, R0,
                                                W1, b1, W2, b2, out, B, N);
}

// Round 2
// 188.907 us; speedup vs baseline: 4.8606x; 4.8606x over previous
//
#include <hip/hip_runtime.h>

// Butterfly sum over a 16-lane DPP row: after 4 stages every lane holds the
// 16-lane sum. quad_perm(1,0,3,2)=0xB1 (xor1), quad_perm(2,3,0,1)=0x4E (xor2),
// row_half_mirror=0x141 (pairs quads within 8), row_mirror=0x140 (pairs 8s).
__device__ __forceinline__ float red16(float v) {
    v += __int_as_float(__builtin_amdgcn_update_dpp(0, __float_as_int(v), 0xB1, 0xF, 0xF, true));
    v += __int_as_float(__builtin_amdgcn_update_dpp(0, __float_as_int(v), 0x4E, 0xF, 0xF, true));
    v += __int_as_float(__builtin_amdgcn_update_dpp(0, __float_as_int(v), 0x141, 0xF, 0xF, true));
    v += __int_as_float(__builtin_amdgcn_update_dpp(0, __float_as_int(v), 0x140, 0xF, 0xF, true));
    return v;
}

__global__ __launch_bounds__(64) void ode_rows16(
    const float* __restrict__ thr,   // B x (N+1)
    const float* __restrict__ DOD,   // B
    const float* __restrict__ Vav,   // B
    const float* __restrict__ C0,    // B
    const float* __restrict__ R0,    // B
    const float* __restrict__ W1,    // 10 x 5
    const float* __restrict__ b1,    // 10
    const float* __restrict__ W2,    // 5 x 10
    const float* __restrict__ b2,    // 5
    float* __restrict__ out,         // B x (N+1) x 2
    int B, int N)
{
    const int lane = threadIdx.x & 63;
    const int grp  = lane >> 4;      // 4 rows per wave
    const int l    = lane & 15;      // hidden-unit index (l<10 active)
    const int row  = blockIdx.x * 4 + grp;
    if (row >= B) return;

    // tanh(x) = 1 - 2/(1+e^{2x}); fold 2*log2(e) into layer-1, "+1" terms
    // into c3/c4, "-2" into layer-2 weights. Each lane owns one hidden unit.
    const float k2 = 2.0f * 1.4426950408889634f;
    float bw = 0.f, w0k = 0.f, w3k = 0.f, w4k = 0.f, w2a = 0.f, w2b = 0.f;
    float cc3 = 0.f, cc4 = 0.f;
    if (l < 10) {
        float w1h1 = W1[l * 5 + 1];
        float w1h2 = W1[l * 5 + 2];
        bw  = k2 * (b1[l] + w1h1 * DOD[row] + w1h2 * Vav[row]);
        w0k = k2 * W1[l * 5 + 0];
        w3k = k2 * W1[l * 5 + 3];
        w4k = k2 * W1[l * 5 + 4];
        float v3 = W2[30 + l];
        float v4 = W2[40 + l];
        cc3 = v3; cc4 = v4;
        w2a = -2.0f * v3;
        w2b = -2.0f * v4;
    }
    const float c3 = b2[3] + red16(cc3);
    const float c4 = b2[4] + red16(cc4);

    float y3 = C0[row], y4 = R0[row];
    const float* trp = thr + (size_t)row * (size_t)(N + 1);
    float2* orow = (float2*)(out + (size_t)row * (size_t)(N + 1) * 2);
    if (l == 0) orow[0] = make_float2(y3, y4);

    // rolling t buffer: tc holds t[16g .. 16g+15] (broadcast: all 16 lanes of
    // the group load the same address -> 1 transaction each)
    float tc[16];
#pragma unroll
    for (int j = 0; j < 16; ++j) tc[j] = trp[min(j, N)];

    const int ngrp = N >> 4;
    for (int g = 0; g < ngrp; ++g) {
        float tn[16];
        const int base = 16 * (g + 1);
#pragma unroll
        for (int j = 0; j < 16; ++j) tn[j] = trp[min(base + j, N)]; // prefetch next group
        float ky3 = 0.f, ky4 = 0.f;
#pragma unroll
        for (int j = 0; j < 16; ++j) {
            float tcu = tc[j];
            float tnx = (j < 15) ? tc[j + 1] : tn[0];
            float h = tnx - tcu;
            float x = fmaf(w0k, tcu, bw);
            x = fmaf(w3k, y3, x);
            x = fmaf(w4k, y4, x);
            float e = __builtin_amdgcn_exp2f(x);       // e^{2*pre}
            float s = __builtin_amdgcn_rcpf(1.0f + e); // sigmoid-ish term
            float ra = red16(w2a * s);
            float rb = red16(w2b * s);
            y3 = fmaf(h, c3, fmaf(h, ra, y3));
            y4 = fmaf(h, c4, fmaf(h, rb, y4));
            if (l == j) { ky3 = y3; ky4 = y4; }        // lane j keeps step j
        }
        // coalesced: 16 lanes store 16 consecutive float2 of this row
        orow[16 * g + l + 1] = make_float2(ky3, ky4);
#pragma unroll
        for (int j = 0; j < 16; ++j) tc[j] = tn[j];
    }

    // tail for N not a multiple of 16 (not taken for N=2048)
    for (int i = 16 * ngrp; i < N; ++i) {
        float tcu = trp[i];
        float tnx = trp[i + 1];
        float h = tnx - tcu;
        float x = fmaf(w0k, tcu, bw);
        x = fmaf(w3k, y3, x);
        x = fmaf(w4k, y4, x);
        float e = __builtin_amdgcn_exp2f(x);
        float s = __builtin_amdgcn_rcpf(1.0f + e);
        float ra = red16(w2a * s);
        float rb = red16(w2b * s);
        y3 = fmaf(h, c3, fmaf(h, ra, y3));
        y4 = fmaf(h, c4, fmaf(h, rb, y4));
        if (l == 0) orow[i + 1] = make_float2(y3, y4);
    }
}

extern "C" void kernel_launch(void* const* d_in, const int* in_sizes, int n_in,
                              void* d_out, int out_size, void* d_ws, size_t ws_size,
                              hipStream_t stream) {
    const float* thr = (const float*)d_in[0];
    const float* DOD = (const float*)d_in[1];
    const float* Vav = (const float*)d_in[2];
    const float* C0  = (const float*)d_in[3];
    const float* R0  = (const float*)d_in[4];
    const float* W1  = (const float*)d_in[5];
    const float* b1  = (const float*)d_in[6];
    const float* W2  = (const float*)d_in[7];
    const float* b2  = (const float*)d_in[8];
    float* out = (float*)d_out;

    int B = in_sizes[1];             // DOD is (1,B)
    int N = in_sizes[0] / B - 1;     // throughput is (B, N+1)

    dim3 block(64);
    dim3 grid((B + 3) / 4);          // 4 rows per 64-thread block (1 wave)
    ode_rows16<<<grid, block, 0, stream>>>(thr, DOD, Vav, C0, R0,
                                           W1, b1, W2, b2, out, B, N);
}

// Round 3
// 166.128 us; speedup vs baseline: 5.5270x; 1.1371x over previous
//
#include <hip/hip_runtime.h>

// Butterfly sum over a 16-lane DPP row: after 4 stages every lane holds the
// 16-lane sum. quad_perm(1,0,3,2)=0xB1 (xor1), quad_perm(2,3,0,1)=0x4E (xor2),
// row_half_mirror=0x141, row_mirror=0x140.
__device__ __forceinline__ float red16(float v) {
    v += __int_as_float(__builtin_amdgcn_update_dpp(0, __float_as_int(v), 0xB1, 0xF, 0xF, true));
    v += __int_as_float(__builtin_amdgcn_update_dpp(0, __float_as_int(v), 0x4E, 0xF, 0xF, true));
    v += __int_as_float(__builtin_amdgcn_update_dpp(0, __float_as_int(v), 0x141, 0xF, 0xF, true));
    v += __int_as_float(__builtin_amdgcn_update_dpp(0, __float_as_int(v), 0x140, 0xF, 0xF, true));
    return v;
}

__global__ __launch_bounds__(64, 1) void ode_rows16(
    const float* __restrict__ thr,   // B x (N+1)
    const float* __restrict__ DOD,   // B
    const float* __restrict__ Vav,   // B
    const float* __restrict__ C0,    // B
    const float* __restrict__ R0,    // B
    const float* __restrict__ W1,    // 10 x 5
    const float* __restrict__ b1,    // 10
    const float* __restrict__ W2,    // 5 x 10
    const float* __restrict__ b2,    // 5
    float* __restrict__ out,         // B x (N+1) x 2
    int B, int N)
{
    const int lane = threadIdx.x & 63;
    const int grp  = lane >> 4;      // 4 rows per wave
    const int l    = lane & 15;      // hidden-unit index (l<10 active)
    const int row  = blockIdx.x * 4 + grp;
    if (row >= B) return;

    // tanh(x) = 1 - 2/(1+e^{2x}); fold 2*log2(e) into layer-1, "+1" terms
    // into c3/c4, "-2" into layer-2 weights. Each lane owns one hidden unit.
    const float k2 = 2.0f * 1.4426950408889634f;
    float bw = 0.f, w0k = 0.f, w3k = 0.f, w4k = 0.f, w2a = 0.f, w2b = 0.f;
    float cc3 = 0.f, cc4 = 0.f;
    if (l < 10) {
        float w1h1 = W1[l * 5 + 1];
        float w1h2 = W1[l * 5 + 2];
        bw  = k2 * (b1[l] + w1h1 * DOD[row] + w1h2 * Vav[row]);
        w0k = k2 * W1[l * 5 + 0];
        w3k = k2 * W1[l * 5 + 3];
        w4k = k2 * W1[l * 5 + 4];
        float v3 = W2[30 + l];
        float v4 = W2[40 + l];
        cc3 = v3; cc4 = v4;
        w2a = -2.0f * v3;
        w2b = -2.0f * v4;
    }
    const float c3 = b2[3] + red16(cc3);
    const float c4 = b2[4] + red16(cc4);

    float y3 = C0[row], y4 = R0[row];
    const float* trp = thr + (size_t)row * (size_t)(N + 1);
    float2* orow = (float2*)(out + (size_t)row * (size_t)(N + 1) * 2);
    if (l == 0) orow[0] = make_float2(y3, y4);

    // Per 16-step group, everything t-dependent is precomputed OFF the
    // y-recurrence chain: b[j] = fma(w0k, t_j, bw), h[j] = t_{j+1}-t_j.
    // The chain loop touches only registers.
    float b[16], h[16];
    {
        float tv[17];
#pragma unroll
        for (int j = 0; j < 17; ++j) tv[j] = trp[min(j, N)];
#pragma unroll
        for (int j = 0; j < 16; ++j) {
            b[j] = fmaf(w0k, tv[j], bw);
            h[j] = tv[j + 1] - tv[j];
        }
    }

    const int ngrp = N >> 4;
    for (int g = 0; g < ngrp; ++g) {
        // issue next group's loads now; ~16 chain-steps (~1400 cyc) cover them
        float tn[17];
        const int nb = 16 * (g + 1);
#pragma unroll
        for (int j = 0; j < 17; ++j) tn[j] = trp[min(nb + j, N)];

        float ky3 = 0.f, ky4 = 0.f;
#pragma unroll
        for (int j = 0; j < 16; ++j) {
            // critical path: 2 fma -> exp2 -> add -> rcp -> mul -> 4 DPP -> fma
            float x = fmaf(w3k, y3, fmaf(w4k, y4, b[j]));
            float e = __builtin_amdgcn_exp2f(x);       // e^{2*pre}
            float s = __builtin_amdgcn_rcpf(1.0f + e);
            float ra = red16(w2a * s);
            float rb = red16(w2b * s);
            y3 = fmaf(h[j], ra, fmaf(h[j], c3, y3));   // inner fma parallel to long path
            y4 = fmaf(h[j], rb, fmaf(h[j], c4, y4));
            if (l == j) { ky3 = y3; ky4 = y4; }        // lane j keeps step j
        }
        // coalesced: 16 lanes store 16 consecutive float2 of this row
        orow[16 * g + l + 1] = make_float2(ky3, ky4);

        // refill b/h for next group (loads have landed by now)
#pragma unroll
        for (int j = 0; j < 16; ++j) {
            b[j] = fmaf(w0k, tn[j], bw);
            h[j] = tn[j + 1] - tn[j];
        }
    }

    // tail for N not a multiple of 16 (not taken for N=2048)
    for (int i = 16 * ngrp; i < N; ++i) {
        float tcu = trp[i];
        float tnx = trp[i + 1];
        float hs = tnx - tcu;
        float x = fmaf(w0k, tcu, bw);
        x = fmaf(w3k, y3, x);
        x = fmaf(w4k, y4, x);
        float e = __builtin_amdgcn_exp2f(x);
        float s = __builtin_amdgcn_rcpf(1.0f + e);
        float ra = red16(w2a * s);
        float rb = red16(w2b * s);
        y3 = fmaf(hs, ra, fmaf(hs, c3, y3));
        y4 = fmaf(hs, rb, fmaf(hs, c4, y4));
        if (l == 0) orow[i + 1] = make_float2(y3, y4);
    }
}

extern "C" void kernel_launch(void* const* d_in, const int* in_sizes, int n_in,
                              void* d_out, int out_size, void* d_ws, size_t ws_size,
                              hipStream_t stream) {
    const float* thr = (const float*)d_in[0];
    const float* DOD = (const float*)d_in[1];
    const float* Vav = (const float*)d_in[2];
    const float* C0  = (const float*)d_in[3];
    const float* R0  = (const float*)d_in[4];
    const float* W1  = (const float*)d_in[5];
    const float* b1  = (const float*)d_in[6];
    const float* W2  = (const float*)d_in[7];
    const float* b2  = (const float*)d_in[8];
    float* out = (float*)d_out;

    int B = in_sizes[1];             // DOD is (1,B)
    int N = in_sizes[0] / B - 1;     // throughput is (B, N+1)

    dim3 block(64);
    dim3 grid((B + 3) / 4);          // 4 rows per 64-thread block (1 wave)
    ode_rows16<<<grid, block, 0, stream>>>(thr, DOD, Vav, C0, R0,
                                           W1, b1, W2, b2, out, B, N);
}

// Round 4
// 146.868 us; speedup vs baseline: 6.2518x; 1.1311x over previous
//
#include <hip/hip_runtime.h>

#define NSWEEP 5

// Inclusive prefix-sum within each 16-lane DPP row: row_shr:1/2/4/8,
// bound_ctrl=true zero-fills lanes shifted in from outside the row.
__device__ __forceinline__ float scan16(float d) {
    d += __int_as_float(__builtin_amdgcn_update_dpp(0, __float_as_int(d), 0x111, 0xF, 0xF, true));
    d += __int_as_float(__builtin_amdgcn_update_dpp(0, __float_as_int(d), 0x112, 0xF, 0xF, true));
    d += __int_as_float(__builtin_amdgcn_update_dpp(0, __float_as_int(d), 0x114, 0xF, 0xF, true));
    d += __int_as_float(__builtin_amdgcn_update_dpp(0, __float_as_int(d), 0x118, 0xF, 0xF, true));
    return d;
}

__global__ __launch_bounds__(64, 1) void ode_waveform(
    const float* __restrict__ thr,   // B x (N+1)
    const float* __restrict__ DOD,   // B
    const float* __restrict__ Vav,   // B
    const float* __restrict__ C0,    // B
    const float* __restrict__ R0,    // B
    const float* __restrict__ W1,    // 10 x 5
    const float* __restrict__ b1,    // 10
    const float* __restrict__ W2,    // 5 x 10
    const float* __restrict__ b2,    // 5
    float* __restrict__ out,         // B x (N+1) x 2
    int B, int N)
{
    const int lane = threadIdx.x & 63;
    const int grp  = lane >> 4;      // 4 rows per wave
    const int j    = lane & 15;      // step-slot within a 16-step block
    const int row  = blockIdx.x * 4 + grp;
    if (row >= B) return;

    // tanh(p) = 1 - 2/(1+e^{2p}); fold 2*log2(e) into layer-1 so exp2 applies
    // directly, fold the "+1" into c3/c4 and the "-2" into wa/wb.
    const float k2 = 2.0f * 1.4426950408889634f;
    const float dod = DOD[row], vav = Vav[row];

    float bw[10], w0k[10], w3k[10], w4k[10], wa[10], wb[10];
    float c3 = b2[3], c4 = b2[4];
#pragma unroll
    for (int h = 0; h < 10; ++h) {
        float a0 = W1[h * 5 + 0];
        float a1 = W1[h * 5 + 1];
        float a2 = W1[h * 5 + 2];
        float a3 = W1[h * 5 + 3];
        float a4 = W1[h * 5 + 4];
        bw[h]  = k2 * (b1[h] + a1 * dod + a2 * vav); // cols 1,2 constant per row
        w0k[h] = k2 * a0;
        w3k[h] = k2 * a3;
        w4k[h] = k2 * a4;
        float v3 = W2[30 + h];
        float v4 = W2[40 + h];
        c3 += v3; c4 += v4;
        wa[h] = -2.0f * v3;
        wb[h] = -2.0f * v4;
    }

    float y03 = C0[row], y04 = R0[row];          // state entering current block
    const float* trp = thr + (size_t)row * (size_t)(N + 1);
    float2* orow = (float2*)(out + (size_t)row * (size_t)(N + 1) * 2);
    if (j == 0) orow[0] = make_float2(y03, y04);

    // t for block 0 (coalesced: lane j loads element base+j)
    float tj  = trp[min(j, N)];
    float tj1 = trp[min(j + 1, N)];

    const int nblk = (N + 15) >> 4;
    for (int g = 0; g < nblk; ++g) {
        const int base = g << 4;
        // prefetch next block's t (lands during the ~1200cy of sweeps)
        const int nb = base + 16;
        float ptj  = trp[min(nb + j, N)];
        float ptj1 = trp[min(nb + j + 1, N)];

        const float hj = tj1 - tj;               // 0 on padded lanes
        float bwt[10];
#pragma unroll
        for (int h = 0; h < 10; ++h) bwt[h] = fmaf(w0k[h], tj, bw[h]);

        // Waveform/Picard sweeps: lane j iterates toward the Euler state at
        // step base+j. Contraction (L*dt_blk)^m/m! ~ 0.16^m/m! -> 5 sweeps
        // is below fp32 noise.
        float z3 = y03, z4 = y04;                // predictor: block-constant
        float S3 = 0.f, S4 = 0.f, d3 = 0.f, d4 = 0.f;
#pragma unroll
        for (int m = 0; m < NSWEEP; ++m) {
            float Fa0 = c3, Fb0 = c4, Fa1 = 0.f, Fb1 = 0.f; // 2 accumulators
#pragma unroll
            for (int h = 0; h < 10; ++h) {
                float x = fmaf(w3k[h], z3, fmaf(w4k[h], z4, bwt[h]));
                float e = __builtin_amdgcn_exp2f(x);       // e^{2*pre}
                float s = __builtin_amdgcn_rcpf(1.0f + e);
                if (h & 1) { Fa1 = fmaf(wa[h], s, Fa1); Fb1 = fmaf(wb[h], s, Fb1); }
                else       { Fa0 = fmaf(wa[h], s, Fa0); Fb0 = fmaf(wb[h], s, Fb0); }
            }
            float F3 = Fa0 + Fa1, F4 = Fb0 + Fb1;
            d3 = hj * F3; d4 = hj * F4;
            S3 = scan16(d3);                      // inclusive prefix of h*F
            S4 = scan16(d4);
            if (m < NSWEEP - 1) {
                z3 = y03 + (S3 - d3);             // exclusive prefix -> state at step j
                z4 = y04 + (S4 - d4);
            }
        }

        // lane j holds the state AFTER step base+j: y0 + inclusive prefix
        if (base + j < N)
            orow[base + j + 1] = make_float2(y03 + S3, y04 + S4);

        // carry the block total (lane 15's inclusive sum) into y0
        y03 += __shfl(S3, 15, 16);
        y04 += __shfl(S4, 15, 16);

        tj = ptj; tj1 = ptj1;
    }
}

extern "C" void kernel_launch(void* const* d_in, const int* in_sizes, int n_in,
                              void* d_out, int out_size, void* d_ws, size_t ws_size,
                              hipStream_t stream) {
    const float* thr = (const float*)d_in[0];
    const float* DOD = (const float*)d_in[1];
    const float* Vav = (const float*)d_in[2];
    const float* C0  = (const float*)d_in[3];
    const float* R0  = (const float*)d_in[4];
    const float* W1  = (const float*)d_in[5];
    const float* b1  = (const float*)d_in[6];
    const float* W2  = (const float*)d_in[7];
    const float* b2  = (const float*)d_in[8];
    float* out = (float*)d_out;

    int B = in_sizes[1];             // DOD is (1,B)
    int N = in_sizes[0] / B - 1;     // throughput is (B, N+1)

    dim3 block(64);
    dim3 grid((B + 3) / 4);          // 4 rows per 64-thread wave
    ode_waveform<<<grid, block, 0, stream>>>(thr, DOD, Vav, C0, R0,
                                             W1, b1, W2, b2, out, B, N);
}

// Round 5
// 105.205 us; speedup vs baseline: 8.7277x; 1.3960x over previous
//
#include <hip/hip_runtime.h>

#define NSWEEP 3

// Inclusive prefix-sum within each 16-lane DPP row: row_shr:1/2/4/8,
// bound_ctrl=true zero-fills lanes shifted in from outside the row.
__device__ __forceinline__ float scan16(float d) {
    d += __int_as_float(__builtin_amdgcn_update_dpp(0, __float_as_int(d), 0x111, 0xF, 0xF, true));
    d += __int_as_float(__builtin_amdgcn_update_dpp(0, __float_as_int(d), 0x112, 0xF, 0xF, true));
    d += __int_as_float(__builtin_amdgcn_update_dpp(0, __float_as_int(d), 0x114, 0xF, 0xF, true));
    d += __int_as_float(__builtin_amdgcn_update_dpp(0, __float_as_int(d), 0x118, 0xF, 0xF, true));
    return d;
}

__global__ __launch_bounds__(64, 1) void ode_waveform(
    const float* __restrict__ thr,   // B x (N+1)
    const float* __restrict__ DOD,   // B
    const float* __restrict__ Vav,   // B
    const float* __restrict__ C0,    // B
    const float* __restrict__ R0,    // B
    const float* __restrict__ W1,    // 10 x 5
    const float* __restrict__ b1,    // 10
    const float* __restrict__ W2,    // 5 x 10
    const float* __restrict__ b2,    // 5
    float* __restrict__ out,         // B x (N+1) x 2
    int B, int N)
{
    const int lane = threadIdx.x & 63;
    const int grp  = lane >> 4;      // 4 rows per wave
    const int j    = lane & 15;      // step-slot within a 16-step block
    const int row  = blockIdx.x * 4 + grp;
    if (row >= B) return;

    // tanh(p) = 1 - 2/(1+e^{2p}); fold 2*log2(e) into layer-1 so exp2 applies
    // directly, fold the "+1" into c3/c4 and the "-2" into wa/wb.
    const float k2 = 2.0f * 1.4426950408889634f;
    const float dod = DOD[row], vav = Vav[row];

    float bw[10], w0k[10], w3k[10], w4k[10], wa[10], wb[10];
    float c3 = b2[3], c4 = b2[4];
#pragma unroll
    for (int h = 0; h < 10; ++h) {
        float a0 = W1[h * 5 + 0];
        float a1 = W1[h * 5 + 1];
        float a2 = W1[h * 5 + 2];
        float a3 = W1[h * 5 + 3];
        float a4 = W1[h * 5 + 4];
        bw[h]  = k2 * (b1[h] + a1 * dod + a2 * vav); // cols 1,2 constant per row
        w0k[h] = k2 * a0;
        w3k[h] = k2 * a3;
        w4k[h] = k2 * a4;
        float v3 = W2[30 + h];
        float v4 = W2[40 + h];
        c3 += v3; c4 += v4;
        wa[h] = -2.0f * v3;
        wb[h] = -2.0f * v4;
    }

    float y03 = C0[row], y04 = R0[row];          // state entering current block
    const float* trp = thr + (size_t)row * (size_t)(N + 1);
    float2* orow = (float2*)(out + (size_t)row * (size_t)(N + 1) * 2);
    if (j == 0) orow[0] = make_float2(y03, y04);

    // t for block 0 (coalesced within the 16-lane group) + block-base t
    float tj  = trp[min(j, N)];
    float tj1 = trp[min(j + 1, N)];
    float t0  = trp[0];

    // bootstrap slope: F(y0, t0) — uniform across lanes
    float F3p, F4p;
    {
        float Fa = c3, Fb = c4;
#pragma unroll
        for (int h = 0; h < 10; ++h) {
            float x = fmaf(w3k[h], y03, fmaf(w4k[h], y04, fmaf(w0k[h], t0, bw[h])));
            float e = __builtin_amdgcn_exp2f(x);
            float s = __builtin_amdgcn_rcpf(1.0f + e);
            Fa = fmaf(wa[h], s, Fa);
            Fb = fmaf(wb[h], s, Fb);
        }
        F3p = Fa; F4p = Fb;
    }

    const int nblk = (N + 15) >> 4;
    for (int g = 0; g < nblk; ++g) {
        const int base = g << 4;
        const int nb = base + 16;
        // prefetch next block's t (lands during the sweeps); pt0 replaces the
        // t0 shuffle with a broadcast load, off the critical path
        float ptj  = trp[min(nb + j, N)];
        float ptj1 = trp[min(nb + j + 1, N)];
        float pt0  = trp[min(nb, N)];

        const float hj = tj1 - tj;               // 0 on clamped lanes
        float bwt[10];
#pragma unroll
        for (int h = 0; h < 10; ++h) bwt[h] = fmaf(w0k[h], tj, bw[h]);

        // first-order predictor: z_j = y0 + (t_j - t0) * F_prev
        const float dt = tj - t0;
        float z3 = fmaf(dt, F3p, y03);
        float z4 = fmaf(dt, F4p, y04);

        float S3 = 0.f, S4 = 0.f, F3 = 0.f, F4 = 0.f;
#pragma unroll
        for (int m = 0; m < NSWEEP; ++m) {
            float Fa0 = c3, Fb0 = c4, Fa1 = 0.f, Fb1 = 0.f;
#pragma unroll
            for (int h = 0; h < 10; ++h) {
                float x = fmaf(w3k[h], z3, fmaf(w4k[h], z4, bwt[h]));
                float e = __builtin_amdgcn_exp2f(x);       // e^{2*pre}
                float s = __builtin_amdgcn_rcpf(1.0f + e);
                if (h & 1) { Fa1 = fmaf(wa[h], s, Fa1); Fb1 = fmaf(wb[h], s, Fb1); }
                else       { Fa0 = fmaf(wa[h], s, Fa0); Fb0 = fmaf(wb[h], s, Fb0); }
            }
            F3 = Fa0 + Fa1; F4 = Fb0 + Fb1;
            float d3 = hj * F3, d4 = hj * F4;
            S3 = scan16(d3);                      // inclusive prefix of h*F
            S4 = scan16(d4);
            if (m < NSWEEP - 1) {
                z3 = y03 + (S3 - d3);             // exclusive prefix -> state at step j
                z4 = y04 + (S4 - d4);
            }
        }

        // lane j holds the state AFTER step base+j
        if (base + j < N)
            orow[base + j + 1] = make_float2(y03 + S3, y04 + S4);

        // carry: block total into y0; last lane's slope into the predictor
        F3p  = __shfl(F3, 15, 16);
        F4p  = __shfl(F4, 15, 16);
        y03 += __shfl(S3, 15, 16);
        y04 += __shfl(S4, 15, 16);

        tj = ptj; tj1 = ptj1; t0 = pt0;
    }
}

extern "C" void kernel_launch(void* const* d_in, const int* in_sizes, int n_in,
                              void* d_out, int out_size, void* d_ws, size_t ws_size,
                              hipStream_t stream) {
    const float* thr = (const float*)d_in[0];
    const float* DOD = (const float*)d_in[1];
    const float* Vav = (const float*)d_in[2];
    const float* C0  = (const float*)d_in[3];
    const float* R0  = (const float*)d_in[4];
    const float* W1  = (const float*)d_in[5];
    const float* b1  = (const float*)d_in[6];
    const float* W2  = (const float*)d_in[7];
    const float* b2  = (const float*)d_in[8];
    float* out = (float*)d_out;

    int B = in_sizes[1];             // DOD is (1,B)
    int N = in_sizes[0] / B - 1;     // throughput is (B, N+1)

    dim3 block(64);
    dim3 grid((B + 3) / 4);          // 4 rows per 64-thread wave
    ode_waveform<<<grid, block, 0, stream>>>(thr, DOD, Vav, C0, R0,
                                             W1, b1, W2, b2, out, B, N);
}

// Round 6
// 92.560 us; speedup vs baseline: 9.9200x; 1.1366x over previous
//
#include <hip/hip_runtime.h>

#define NSWEEP 3

// Inclusive prefix-sum within each 32-lane half-wave.
// Stages 1-4: row_shr:1/2/4/8 within 16-lane DPP rows (bound_ctrl zero-fills).
// Stage 5: row_bcast15 (0x142) adds lane15 -> lanes 16-31 and lane47 ->
// lanes 48-63; row_mask=0xA updates only rows 1,3 (others take old=0), so the
// two 32-lane groups (two ODE rows) stay independent.
__device__ __forceinline__ float scan32(float d) {
    d += __int_as_float(__builtin_amdgcn_update_dpp(0, __float_as_int(d), 0x111, 0xF, 0xF, true));
    d += __int_as_float(__builtin_amdgcn_update_dpp(0, __float_as_int(d), 0x112, 0xF, 0xF, true));
    d += __int_as_float(__builtin_amdgcn_update_dpp(0, __float_as_int(d), 0x114, 0xF, 0xF, true));
    d += __int_as_float(__builtin_amdgcn_update_dpp(0, __float_as_int(d), 0x118, 0xF, 0xF, true));
    d += __int_as_float(__builtin_amdgcn_update_dpp(0, __float_as_int(d), 0x142, 0xA, 0xF, true));
    return d;
}

__global__ __launch_bounds__(64, 1) void ode_waveform32(
    const float* __restrict__ thr,   // B x (N+1)
    const float* __restrict__ DOD,   // B
    const float* __restrict__ Vav,   // B
    const float* __restrict__ C0,    // B
    const float* __restrict__ R0,    // B
    const float* __restrict__ W1,    // 10 x 5
    const float* __restrict__ b1,    // 10
    const float* __restrict__ W2,    // 5 x 10
    const float* __restrict__ b2,    // 5
    float* __restrict__ out,         // B x (N+1) x 2
    int B, int N)
{
    const int lane = threadIdx.x & 63;
    const int grp  = lane >> 5;      // 2 rows per wave
    const int j    = lane & 31;      // step-slot within a 32-step block
    const int row  = blockIdx.x * 2 + grp;
    if (row >= B) return;

    // tanh(p) = 1 - 2/(1+e^{2p}); fold 2*log2(e) into layer-1 so exp2 applies
    // directly, fold the "+1" into c3/c4 and the "-2" into wa/wb.
    const float k2 = 2.0f * 1.4426950408889634f;
    const float dod = DOD[row], vav = Vav[row];

    float bw[10], w0k[10], w3k[10], w4k[10], wa[10], wb[10];
    float c3 = b2[3], c4 = b2[4];
#pragma unroll
    for (int h = 0; h < 10; ++h) {
        float a0 = W1[h * 5 + 0];
        float a1 = W1[h * 5 + 1];
        float a2 = W1[h * 5 + 2];
        float a3 = W1[h * 5 + 3];
        float a4 = W1[h * 5 + 4];
        bw[h]  = k2 * (b1[h] + a1 * dod + a2 * vav); // cols 1,2 constant per row
        w0k[h] = k2 * a0;
        w3k[h] = k2 * a3;
        w4k[h] = k2 * a4;
        float v3 = W2[30 + h];
        float v4 = W2[40 + h];
        c3 += v3; c4 += v4;
        wa[h] = -2.0f * v3;
        wb[h] = -2.0f * v4;
    }

    float y03 = C0[row], y04 = R0[row];          // state entering current block
    const float* trp = thr + (size_t)row * (size_t)(N + 1);
    float2* orow = (float2*)(out + (size_t)row * (size_t)(N + 1) * 2);
    if (j == 0) orow[0] = make_float2(y03, y04);

    // t for block 0 (coalesced within the 32-lane group) + block-base t
    float tj  = trp[min(j, N)];
    float tj1 = trp[min(j + 1, N)];
    float t0  = trp[0];

    // bootstrap slope: F(y0, t0) — uniform across the group
    float F3p, F4p;
    {
        float Fa = c3, Fb = c4;
#pragma unroll
        for (int h = 0; h < 10; ++h) {
            float x = fmaf(w3k[h], y03, fmaf(w4k[h], y04, fmaf(w0k[h], t0, bw[h])));
            float e = __builtin_amdgcn_exp2f(x);
            float s = __builtin_amdgcn_rcpf(1.0f + e);
            Fa = fmaf(wa[h], s, Fa);
            Fb = fmaf(wb[h], s, Fb);
        }
        F3p = Fa; F4p = Fb;
    }

    const int nblk = (N + 31) >> 5;
    for (int g = 0; g < nblk; ++g) {
        const int base = g << 5;
        const int nb = base + 32;
        // prefetch next block's t (lands during the sweeps)
        float ptj  = trp[min(nb + j, N)];
        float ptj1 = trp[min(nb + j + 1, N)];
        float pt0  = trp[min(nb, N)];

        const float hj = tj1 - tj;               // 0 on clamped lanes
        float bwt[10];
#pragma unroll
        for (int h = 0; h < 10; ++h) bwt[h] = fmaf(w0k[h], tj, bw[h]);

        // first-order predictor: z_j = y0 + (t_j - t0) * F_prev
        const float dt = tj - t0;
        float z3 = fmaf(dt, F3p, y03);
        float z4 = fmaf(dt, F4p, y04);

        float S3 = 0.f, S4 = 0.f, F3 = 0.f, F4 = 0.f;
#pragma unroll
        for (int m = 0; m < NSWEEP; ++m) {
            float Fa0 = c3, Fb0 = c4, Fa1 = 0.f, Fb1 = 0.f;
#pragma unroll
            for (int h = 0; h < 10; ++h) {
                float x = fmaf(w3k[h], z3, fmaf(w4k[h], z4, bwt[h]));
                float e = __builtin_amdgcn_exp2f(x);       // e^{2*pre}
                float s = __builtin_amdgcn_rcpf(1.0f + e);
                if (h & 1) { Fa1 = fmaf(wa[h], s, Fa1); Fb1 = fmaf(wb[h], s, Fb1); }
                else       { Fa0 = fmaf(wa[h], s, Fa0); Fb0 = fmaf(wb[h], s, Fb0); }
            }
            F3 = Fa0 + Fa1; F4 = Fb0 + Fb1;
            float d3 = hj * F3, d4 = hj * F4;
            S3 = scan32(d3);                      // inclusive prefix of h*F
            S4 = scan32(d4);
            if (m < NSWEEP - 1) {
                z3 = y03 + (S3 - d3);             // exclusive prefix -> state at step j
                z4 = y04 + (S4 - d4);
            }
        }

        // lane j holds the state AFTER step base+j
        if (base + j < N)
            orow[base + j + 1] = make_float2(y03 + S3, y04 + S4);

        // carry: group total into y0; last lane's slope into the predictor
        F3p  = __shfl(F3, 31, 32);
        F4p  = __shfl(F4, 31, 32);
        y03 += __shfl(S3, 31, 32);
        y04 += __shfl(S4, 31, 32);

        tj = ptj; tj1 = ptj1; t0 = pt0;
    }
}

extern "C" void kernel_launch(void* const* d_in, const int* in_sizes, int n_in,
                              void* d_out, int out_size, void* d_ws, size_t ws_size,
                              hipStream_t stream) {
    const float* thr = (const float*)d_in[0];
    const float* DOD = (const float*)d_in[1];
    const float* Vav = (const float*)d_in[2];
    const float* C0  = (const float*)d_in[3];
    const float* R0  = (const float*)d_in[4];
    const float* W1  = (const float*)d_in[5];
    const float* b1  = (const float*)d_in[6];
    const float* W2  = (const float*)d_in[7];
    const float* b2  = (const float*)d_in[8];
    float* out = (float*)d_out;

    int B = in_sizes[1];             // DOD is (1,B)
    int N = in_sizes[0] / B - 1;     // throughput is (B, N+1)

    dim3 block(64);
    dim3 grid((B + 1) / 2);          // 2 rows per 64-thread wave
    ode_waveform32<<<grid, block, 0, stream>>>(thr, DOD, Vav, C0, R0,
                                               W1, b1, W2, b2, out, B, N);
}

// Round 7
// 90.805 us; speedup vs baseline: 10.1117x; 1.0193x over previous
//
#include <hip/hip_runtime.h>

#define NSWEEP 3

// Canonical wave64 inclusive prefix-sum (AMD GCN scan sequence).
// row_shr:1/2/4/8 within 16-lane rows (bound_ctrl zero-fills), then
// row_bcast15 (0x142, row_mask 0xA: rows 1,3 take lane15/47 of prior row),
// then row_bcast31 (0x143, row_mask 0xC: rows 2,3 take lane31).
__device__ __forceinline__ float scan64(float d) {
    d += __int_as_float(__builtin_amdgcn_update_dpp(0, __float_as_int(d), 0x111, 0xF, 0xF, true));
    d += __int_as_float(__builtin_amdgcn_update_dpp(0, __float_as_int(d), 0x112, 0xF, 0xF, true));
    d += __int_as_float(__builtin_amdgcn_update_dpp(0, __float_as_int(d), 0x114, 0xF, 0xF, true));
    d += __int_as_float(__builtin_amdgcn_update_dpp(0, __float_as_int(d), 0x118, 0xF, 0xF, true));
    d += __int_as_float(__builtin_amdgcn_update_dpp(0, __float_as_int(d), 0x142, 0xA, 0xF, true));
    d += __int_as_float(__builtin_amdgcn_update_dpp(0, __float_as_int(d), 0x143, 0xC, 0xF, true));
    return d;
}

__global__ __launch_bounds__(64, 1) void ode_waveform64(
    const float* __restrict__ thr,   // B x (N+1)
    const float* __restrict__ DOD,   // B
    const float* __restrict__ Vav,   // B
    const float* __restrict__ C0,    // B
    const float* __restrict__ R0,    // B
    const float* __restrict__ W1,    // 10 x 5
    const float* __restrict__ b1,    // 10
    const float* __restrict__ W2,    // 5 x 10
    const float* __restrict__ b2,    // 5
    float* __restrict__ out,         // B x (N+1) x 2
    int B, int N)
{
    const int j   = threadIdx.x & 63;   // step-slot within a 64-step block
    const int row = blockIdx.x;         // 1 row per wave
    if (row >= B) return;

    // tanh(p) = 1 - 2/(1+e^{2p}); fold 2*log2(e) into layer-1 so exp2 applies
    // directly, fold the "+1" into c3/c4 and the "-2" into wa/wb.
    const float k2 = 2.0f * 1.4426950408889634f;
    const float dod = DOD[row], vav = Vav[row];

    float bw[10], w0k[10], w3k[10], w4k[10], wa[10], wb[10];
    float c3 = b2[3], c4 = b2[4];
#pragma unroll
    for (int h = 0; h < 10; ++h) {
        float a0 = W1[h * 5 + 0];
        float a1 = W1[h * 5 + 1];
        float a2 = W1[h * 5 + 2];
        float a3 = W1[h * 5 + 3];
        float a4 = W1[h * 5 + 4];
        bw[h]  = k2 * (b1[h] + a1 * dod + a2 * vav); // cols 1,2 constant per row
        w0k[h] = k2 * a0;
        w3k[h] = k2 * a3;
        w4k[h] = k2 * a4;
        float v3 = W2[30 + h];
        float v4 = W2[40 + h];
        c3 += v3; c4 += v4;
        wa[h] = -2.0f * v3;
        wb[h] = -2.0f * v4;
    }

    float y03 = C0[row], y04 = R0[row];          // state entering current block
    const float* trp = thr + (size_t)row * (size_t)(N + 1);
    float2* orow = (float2*)(out + (size_t)row * (size_t)(N + 1) * 2);
    if (j == 0) orow[0] = make_float2(y03, y04);

    // t for block 0 (coalesced across the wave) + block-base t
    float tj  = trp[min(j, N)];
    float tj1 = trp[min(j + 1, N)];
    float t0  = trp[0];

    // bootstrap slope: F(y0, t0) — uniform across the wave
    float F3p, F4p;
    {
        float Fa = c3, Fb = c4;
#pragma unroll
        for (int h = 0; h < 10; ++h) {
            float x = fmaf(w3k[h], y03, fmaf(w4k[h], y04, fmaf(w0k[h], t0, bw[h])));
            float e = __builtin_amdgcn_exp2f(x);
            float s = __builtin_amdgcn_rcpf(1.0f + e);
            Fa = fmaf(wa[h], s, Fa);
            Fb = fmaf(wb[h], s, Fb);
        }
        F3p = Fa; F4p = Fb;
    }
    float dF3 = 0.f, dF4 = 0.f;                  // slope rate (2nd-order predictor)

    const int nblk = (N + 63) >> 6;
    for (int g = 0; g < nblk; ++g) {
        const int base = g << 6;
        const int nb = base + 64;
        // prefetch next block's t (lands during the sweeps)
        float ptj  = trp[min(nb + j, N)];
        float ptj1 = trp[min(nb + j + 1, N)];
        float pt0  = trp[min(nb, N)];

        const float hj = tj1 - tj;               // 0 on clamped lanes
        float bwt[10];
#pragma unroll
        for (int h = 0; h < 10; ++h) bwt[h] = fmaf(w0k[h], tj, bw[h]);

        // 2nd-order predictor: z_j = y0 + dt*(F_prev + 0.5*dt*dF)
        const float dt = tj - t0;
        float z3 = fmaf(dt, fmaf(0.5f * dt, dF3, F3p), y03);
        float z4 = fmaf(dt, fmaf(0.5f * dt, dF4, F4p), y04);

        float S3 = 0.f, S4 = 0.f, F3 = 0.f, F4 = 0.f;
#pragma unroll
        for (int m = 0; m < NSWEEP; ++m) {
            float Fa0 = c3, Fb0 = c4, Fa1 = 0.f, Fb1 = 0.f;
#pragma unroll
            for (int h = 0; h < 10; ++h) {
                float x = fmaf(w3k[h], z3, fmaf(w4k[h], z4, bwt[h]));
                float e = __builtin_amdgcn_exp2f(x);       // e^{2*pre}
                float s = __builtin_amdgcn_rcpf(1.0f + e);
                if (h & 1) { Fa1 = fmaf(wa[h], s, Fa1); Fb1 = fmaf(wb[h], s, Fb1); }
                else       { Fa0 = fmaf(wa[h], s, Fa0); Fb0 = fmaf(wb[h], s, Fb0); }
            }
            F3 = Fa0 + Fa1; F4 = Fb0 + Fb1;
            float d3 = hj * F3, d4 = hj * F4;
            S3 = scan64(d3);                      // inclusive prefix of h*F
            S4 = scan64(d4);
            if (m < NSWEEP - 1) {
                z3 = y03 + (S3 - d3);             // exclusive prefix -> state at step j
                z4 = y04 + (S4 - d4);
            }
        }

        // lane j holds the state AFTER step base+j
        if (base + j < N)
            orow[base + j + 1] = make_float2(y03 + S3, y04 + S4);

        // carry: block total into y0; lane63 slope + slope-rate into predictor
        float F3n = __shfl(F3, 63, 64);
        float F4n = __shfl(F4, 63, 64);
        y03 += __shfl(S3, 63, 64);
        y04 += __shfl(S4, 63, 64);
        float span = pt0 - t0;
        float inv = (span > 0.f) ? __builtin_amdgcn_rcpf(span) : 0.f;
        dF3 = (F3n - F3p) * inv;
        dF4 = (F4n - F4p) * inv;
        F3p = F3n; F4p = F4n;

        tj = ptj; tj1 = ptj1; t0 = pt0;
    }
}

extern "C" void kernel_launch(void* const* d_in, const int* in_sizes, int n_in,
                              void* d_out, int out_size, void* d_ws, size_t ws_size,
                              hipStream_t stream) {
    const float* thr = (const float*)d_in[0];
    const float* DOD = (const float*)d_in[1];
    const float* Vav = (const float*)d_in[2];
    const float* C0  = (const float*)d_in[3];
    const float* R0  = (const float*)d_in[4];
    const float* W1  = (const float*)d_in[5];
    const float* b1  = (const float*)d_in[6];
    const float* W2  = (const float*)d_in[7];
    const float* b2  = (const float*)d_in[8];
    float* out = (float*)d_out;

    int B = in_sizes[1];             // DOD is (1,B)
    int N = in_sizes[0] / B - 1;     // throughput is (B, N+1)

    dim3 block(64);
    dim3 grid(B);                    // 1 row per 64-thread wave
    ode_waveform64<<<grid, block, 0, stream>>>(thr, DOD, Vav, C0, R0,
                                               W1, b1, W2, b2, out, B, N);
}

// Round 8
// 67.427 us; speedup vs baseline: 13.6175x; 1.3467x over previous
//
#include <hip/hip_runtime.h>

#define NSWEEP 2

// Canonical wave64 inclusive prefix-sum (AMD GCN scan sequence).
// row_shr:1/2/4/8 within 16-lane rows (bound_ctrl zero-fills), then
// row_bcast15 (0x142, row_mask 0xA: rows 1,3 take lane15/47 of prior row),
// then row_bcast31 (0x143, row_mask 0xC: rows 2,3 take lane31).
__device__ __forceinline__ float scan64(float d) {
    d += __int_as_float(__builtin_amdgcn_update_dpp(0, __float_as_int(d), 0x111, 0xF, 0xF, true));
    d += __int_as_float(__builtin_amdgcn_update_dpp(0, __float_as_int(d), 0x112, 0xF, 0xF, true));
    d += __int_as_float(__builtin_amdgcn_update_dpp(0, __float_as_int(d), 0x114, 0xF, 0xF, true));
    d += __int_as_float(__builtin_amdgcn_update_dpp(0, __float_as_int(d), 0x118, 0xF, 0xF, true));
    d += __int_as_float(__builtin_amdgcn_update_dpp(0, __float_as_int(d), 0x142, 0xA, 0xF, true));
    d += __int_as_float(__builtin_amdgcn_update_dpp(0, __float_as_int(d), 0x143, 0xC, 0xF, true));
    return d;
}

__global__ __launch_bounds__(64, 1) void ode_waveform64(
    const float* __restrict__ thr,   // B x (N+1)
    const float* __restrict__ DOD,   // B
    const float* __restrict__ Vav,   // B
    const float* __restrict__ C0,    // B
    const float* __restrict__ R0,    // B
    const float* __restrict__ W1,    // 10 x 5
    const float* __restrict__ b1,    // 10
    const float* __restrict__ W2,    // 5 x 10
    const float* __restrict__ b2,    // 5
    float* __restrict__ out,         // B x (N+1) x 2
    int B, int N)
{
    const int j   = threadIdx.x & 63;   // step-slot within a 64-step block
    const int row = blockIdx.x;         // 1 row per wave
    if (row >= B) return;

    // tanh(p) = 1 - 2/(1+e^{2p}); fold 2*log2(e) into layer-1 so exp2 applies
    // directly, fold the "+1" into c3/c4 and the "-2" into wa/wb.
    const float k2 = 2.0f * 1.4426950408889634f;
    const float dod = DOD[row], vav = Vav[row];

    float bw[10], w0k[10], w3k[10], w4k[10], wa[10], wb[10];
    float c3 = b2[3], c4 = b2[4];
#pragma unroll
    for (int h = 0; h < 10; ++h) {
        float a0 = W1[h * 5 + 0];
        float a1 = W1[h * 5 + 1];
        float a2 = W1[h * 5 + 2];
        float a3 = W1[h * 5 + 3];
        float a4 = W1[h * 5 + 4];
        bw[h]  = k2 * (b1[h] + a1 * dod + a2 * vav); // cols 1,2 constant per row
        w0k[h] = k2 * a0;
        w3k[h] = k2 * a3;
        w4k[h] = k2 * a4;
        float v3 = W2[30 + h];
        float v4 = W2[40 + h];
        c3 += v3; c4 += v4;
        wa[h] = -2.0f * v3;
        wb[h] = -2.0f * v4;
    }

    float y03 = C0[row], y04 = R0[row];          // state entering current block
    const float* trp = thr + (size_t)row * (size_t)(N + 1);
    float2* orow = (float2*)(out + (size_t)row * (size_t)(N + 1) * 2);
    if (j == 0) orow[0] = make_float2(y03, y04);

    // t for block 0 (coalesced across the wave) + block-base t
    float tj  = trp[min(j, N)];
    float tj1 = trp[min(j + 1, N)];
    float t0  = trp[0];

    // bootstrap slope: F(y0, t0) — uniform across the wave
    float F3p, F4p;
    {
        float Fa = c3, Fb = c4;
#pragma unroll
        for (int h = 0; h < 10; ++h) {
            float x = fmaf(w3k[h], y03, fmaf(w4k[h], y04, fmaf(w0k[h], t0, bw[h])));
            float e = __builtin_amdgcn_exp2f(x);
            float s = __builtin_amdgcn_rcpf(1.0f + e);
            Fa = fmaf(wa[h], s, Fa);
            Fb = fmaf(wb[h], s, Fb);
        }
        F3p = Fa; F4p = Fb;
    }
    float dF3 = 0.f, dF4 = 0.f;                  // slope rate (2nd-order predictor)

    const int nblk = (N + 63) >> 6;
    for (int g = 0; g < nblk; ++g) {
        const int base = g << 6;
        const int nb = base + 64;
        // prefetch next block's t (lands during the sweeps)
        float ptj  = trp[min(nb + j, N)];
        float ptj1 = trp[min(nb + j + 1, N)];
        float pt0  = trp[min(nb, N)];

        const float hj = tj1 - tj;               // 0 on clamped lanes
        float bwt[10];
#pragma unroll
        for (int h = 0; h < 10; ++h) bwt[h] = fmaf(w0k[h], tj, bw[h]);

        // 2nd-order predictor: z_j = y0 + dt*(F_prev + 0.5*dt*dF)
        const float dt = tj - t0;
        float z3 = fmaf(dt, fmaf(0.5f * dt, dF3, F3p), y03);
        float z4 = fmaf(dt, fmaf(0.5f * dt, dF4, F4p), y04);

        float S3 = 0.f, S4 = 0.f, F3 = 0.f, F4 = 0.f;
#pragma unroll
        for (int m = 0; m < NSWEEP; ++m) {
            float Fa0 = c3, Fb0 = c4, Fa1 = 0.f, Fb1 = 0.f;
#pragma unroll
            for (int h = 0; h < 10; ++h) {
                float x = fmaf(w3k[h], z3, fmaf(w4k[h], z4, bwt[h]));
                float e = __builtin_amdgcn_exp2f(x);       // e^{2*pre}
                float s = __builtin_amdgcn_rcpf(1.0f + e);
                if (h & 1) { Fa1 = fmaf(wa[h], s, Fa1); Fb1 = fmaf(wb[h], s, Fb1); }
                else       { Fa0 = fmaf(wa[h], s, Fa0); Fb0 = fmaf(wb[h], s, Fb0); }
            }
            F3 = Fa0 + Fa1; F4 = Fb0 + Fb1;
            float d3 = hj * F3, d4 = hj * F4;
            S3 = scan64(d3);                      // inclusive prefix of h*F
            S4 = scan64(d4);
            if (m < NSWEEP - 1) {
                z3 = y03 + (S3 - d3);             // exclusive prefix -> state at step j
                z4 = y04 + (S4 - d4);
            }
        }

        // lane j holds the state AFTER step base+j
        if (base + j < N)
            orow[base + j + 1] = make_float2(y03 + S3, y04 + S4);

        // carry: block total into y0; lane63 slope + slope-rate into predictor
        float F3n = __shfl(F3, 63, 64);
        float F4n = __shfl(F4, 63, 64);
        y03 += __shfl(S3, 63, 64);
        y04 += __shfl(S4, 63, 64);
        float span = pt0 - t0;
        float inv = (span > 0.f) ? __builtin_amdgcn_rcpf(span) : 0.f;
        dF3 = (F3n - F3p) * inv;
        dF4 = (F4n - F4p) * inv;
        F3p = F3n; F4p = F4n;

        tj = ptj; tj1 = ptj1; t0 = pt0;
    }
}

extern "C" void kernel_launch(void* const* d_in, const int* in_sizes, int n_in,
                              void* d_out, int out_size, void* d_ws, size_t ws_size,
                              hipStream_t stream) {
    const float* thr = (const float*)d_in[0];
    const float* DOD = (const float*)d_in[1];
    const float* Vav = (const float*)d_in[2];
    const float* C0  = (const float*)d_in[3];
    const float* R0  = (const float*)d_in[4];
    const float* W1  = (const float*)d_in[5];
    const float* b1  = (const float*)d_in[6];
    const float* W2  = (const float*)d_in[7];
    const float* b2  = (const float*)d_in[8];
    float* out = (float*)d_out;

    int B = in_sizes[1];             // DOD is (1,B)
    int N = in_sizes[0] / B - 1;     // throughput is (B, N+1)

    dim3 block(64);
    dim3 grid(B);                    // 1 row per 64-thread wave
    ode_waveform64<<<grid, block, 0, stream>>>(thr, DOD, Vav, C0, R0,
                                               W1, b1, W2, b2, out, B, N);
}

// Round 9
// 62.030 us; speedup vs baseline: 14.8024x; 1.0870x over previous
//
#include <hip/hip_runtime.h>

#define NSWEEP 2

typedef float v2f __attribute__((ext_vector_type(2)));

// Canonical wave64 inclusive prefix-sum (AMD GCN scan sequence).
// row_shr:1/2/4/8 within 16-lane rows (bound_ctrl zero-fills), then
// row_bcast15 (0x142, row_mask 0xA) and row_bcast31 (0x143, row_mask 0xC).
__device__ __forceinline__ float scan64(float d) {
    d += __int_as_float(__builtin_amdgcn_update_dpp(0, __float_as_int(d), 0x111, 0xF, 0xF, true));
    d += __int_as_float(__builtin_amdgcn_update_dpp(0, __float_as_int(d), 0x112, 0xF, 0xF, true));
    d += __int_as_float(__builtin_amdgcn_update_dpp(0, __float_as_int(d), 0x114, 0xF, 0xF, true));
    d += __int_as_float(__builtin_amdgcn_update_dpp(0, __float_as_int(d), 0x118, 0xF, 0xF, true));
    d += __int_as_float(__builtin_amdgcn_update_dpp(0, __float_as_int(d), 0x142, 0xA, 0xF, true));
    d += __int_as_float(__builtin_amdgcn_update_dpp(0, __float_as_int(d), 0x143, 0xC, 0xF, true));
    return d;
}

__global__ __launch_bounds__(64, 4) void ode_waveform64(
    const float* __restrict__ thr,   // B x (N+1)
    const float* __restrict__ DOD,   // B
    const float* __restrict__ Vav,   // B
    const float* __restrict__ C0,    // B
    const float* __restrict__ R0,    // B
    const float* __restrict__ W1,    // 10 x 5
    const float* __restrict__ b1,    // 10
    const float* __restrict__ W2,    // 5 x 10
    const float* __restrict__ b2,    // 5
    float* __restrict__ out,         // B x (N+1) x 2
    int B, int N)
{
    const int j   = threadIdx.x & 63;   // step-slot within a 64-step block
    const int row = blockIdx.x;         // 1 row per wave
    if (row >= B) return;

    // tanh(p) = 1 - 2/(1+e^{2p}); fold 2*log2(e) into layer-1 so exp2 applies
    // directly, fold the "+1" into c3/c4 and the "-2" into wa/wb.
    // Hidden units packed in pairs (h, h+5) -> v_pk_fma_f32 / v_pk_add_f32.
    const float k2 = 2.0f * 1.4426950408889634f;
    const float dod = DOD[row], vav = Vav[row];

    v2f bw[5], w0k[5], w3k[5], w4k[5], wa[5], wb[5];
    float c3 = b2[3], c4 = b2[4];
#pragma unroll
    for (int i = 0; i < 5; ++i) {
#pragma unroll
        for (int p = 0; p < 2; ++p) {
            int h = i + 5 * p;
            float a0 = W1[h * 5 + 0];
            float a1 = W1[h * 5 + 1];
            float a2 = W1[h * 5 + 2];
            float a3 = W1[h * 5 + 3];
            float a4 = W1[h * 5 + 4];
            bw[i][p]  = k2 * (b1[h] + a1 * dod + a2 * vav);
            w0k[i][p] = k2 * a0;
            w3k[i][p] = k2 * a3;
            w4k[i][p] = k2 * a4;
            float v3 = W2[30 + h];
            float v4 = W2[40 + h];
            c3 += v3; c4 += v4;
            wa[i][p] = -2.0f * v3;
            wb[i][p] = -2.0f * v4;
        }
    }

    float y03 = C0[row], y04 = R0[row];          // state entering current block
    const float* trp = thr + (size_t)row * (size_t)(N + 1);
    float2* orow = (float2*)(out + (size_t)row * (size_t)(N + 1) * 2);
    if (j == 0) orow[0] = make_float2(y03, y04);

    // t for block 0 (coalesced across the wave) + block-base t
    float tj  = trp[min(j, N)];
    float tj1 = trp[min(j + 1, N)];
    float t0  = trp[0];

    // bootstrap slope: F(y0, t0) — uniform across the wave
    float F3p, F4p;
    {
        v2f Fa = {c3, 0.f}, Fb = {c4, 0.f};
#pragma unroll
        for (int i = 0; i < 5; ++i) {
            v2f x = w3k[i] * y03 + (w4k[i] * y04 + (w0k[i] * t0 + bw[i]));
            v2f e; e.x = __builtin_amdgcn_exp2f(x.x); e.y = __builtin_amdgcn_exp2f(x.y);
            v2f A = e + 1.0f;
            v2f s; s.x = __builtin_amdgcn_rcpf(A.x); s.y = __builtin_amdgcn_rcpf(A.y);
            Fa += wa[i] * s;
            Fb += wb[i] * s;
        }
        F3p = Fa.x + Fa.y; F4p = Fb.x + Fb.y;
    }
    float dF3 = 0.f, dF4 = 0.f;                  // slope rate (2nd-order predictor)

    const int nblk = (N + 63) >> 6;
    const int gInt = max(0, (N + 1) / 64 - 1);   // interior blocks: no clamps needed

    int g = 0;
    float S3 = 0.f, S4 = 0.f, F3, F4;

#define BLOCK_BODY(LOAD_PT, STORE)                                            \
    {                                                                         \
        const int base = g << 6;                                              \
        const int nb = base + 64;                                             \
        LOAD_PT;                                                              \
        const float hj = tj1 - tj;                                            \
        v2f bwt[5];                                                           \
        _Pragma("unroll")                                                     \
        for (int i = 0; i < 5; ++i) bwt[i] = w0k[i] * tj + bw[i];             \
        const float dt = tj - t0;                                             \
        float z3 = fmaf(dt, fmaf(0.5f * dt, dF3, F3p), y03);                  \
        float z4 = fmaf(dt, fmaf(0.5f * dt, dF4, F4p), y04);                  \
        _Pragma("unroll")                                                     \
        for (int m = 0; m < NSWEEP; ++m) {                                    \
            v2f Fa = {c3, 0.f}, Fb = {c4, 0.f};                               \
            _Pragma("unroll")                                                 \
            for (int i = 0; i < 5; ++i) {                                     \
                v2f x = w3k[i] * z3 + (w4k[i] * z4 + bwt[i]);                 \
                v2f e; e.x = __builtin_amdgcn_exp2f(x.x);                     \
                       e.y = __builtin_amdgcn_exp2f(x.y);                     \
                v2f A = e + 1.0f;                                             \
                v2f s; s.x = __builtin_amdgcn_rcpf(A.x);                      \
                       s.y = __builtin_amdgcn_rcpf(A.y);                      \
                Fa += wa[i] * s;                                              \
                Fb += wb[i] * s;                                              \
            }                                                                 \
            F3 = Fa.x + Fa.y; F4 = Fb.x + Fb.y;                               \
            float d3 = hj * F3, d4 = hj * F4;                                 \
            S3 = scan64(d3);                                                  \
            S4 = scan64(d4);                                                  \
            if (m < NSWEEP - 1) {                                             \
                z3 = y03 + (S3 - d3);                                         \
                z4 = y04 + (S4 - d4);                                         \
            }                                                                 \
        }                                                                     \
        STORE;                                                                \
        float F3n = __shfl(F3, 63, 64);                                       \
        float F4n = __shfl(F4, 63, 64);                                       \
        y03 += __shfl(S3, 63, 64);                                            \
        y04 += __shfl(S4, 63, 64);                                            \
        float span = pt0 - t0;                                                \
        float inv = (span > 0.f) ? __builtin_amdgcn_rcpf(span) : 0.f;         \
        dF3 = (F3n - F3p) * inv;                                              \
        dF4 = (F4n - F4p) * inv;                                              \
        F3p = F3n; F4p = F4n;                                                 \
        tj = ptj; tj1 = ptj1; t0 = pt0;                                       \
    }

    // interior blocks: unconditional loads (nb+64 <= N+1) and stores
    for (; g < gInt; ++g)
        BLOCK_BODY(
            float ptj = trp[nb + j]; float ptj1 = trp[nb + j + 1];
            float pt0 = trp[nb],
            orow[base + j + 1] = make_float2(y03 + S3, y04 + S4))

    // tail block(s): clamped loads, guarded store
    for (; g < nblk; ++g)
        BLOCK_BODY(
            float ptj = trp[min(nb + j, N)]; float ptj1 = trp[min(nb + j + 1, N)];
            float pt0 = trp[min(nb, N)],
            if (base + j < N) orow[base + j + 1] = make_float2(y03 + S3, y04 + S4))

#undef BLOCK_BODY
}

extern "C" void kernel_launch(void* const* d_in, const int* in_sizes, int n_in,
                              void* d_out, int out_size, void* d_ws, size_t ws_size,
                              hipStream_t stream) {
    const float* thr = (const float*)d_in[0];
    const float* DOD = (const float*)d_in[1];
    const float* Vav = (const float*)d_in[2];
    const float* C0  = (const float*)d_in[3];
    const float* R0  = (const float*)d_in[4];
    const float* W1  = (const float*)d_in[5];
    const float* b1  = (const float*)d_in[6];
    const float* W2  = (const float*)d_in[7];
    const float* b2  = (const float*)d_in[8];
    float* out = (float*)d_out;

    int B = in_sizes[1];             // DOD is (1,B)
    int N = in_sizes[0] / B - 1;     // throughput is (B, N+1)

    dim3 block(64);
    dim3 grid(B);                    // 1 row per 64-thread wave
    ode_waveform64<<<grid, block, 0, stream>>>(thr, DOD, Vav, C0, R0,
                                               W1, b1, W2, b2, out, B, N);
}